// Round 13
// baseline (107.023 us; speedup 1.0000x reference)
//
#include <hip/hip_runtime.h>
#include <hip/hip_bf16.h>

typedef __bf16 bf16x8 __attribute__((ext_vector_type(8)));
typedef float  f32x4  __attribute__((ext_vector_type(4)));

#define NN 4096
#define DK 128
#define NMAX 0.99f
#define LN2F 0.69314718056f

// frag-major bf16 image, per batch (1 MB): [rowblk 0..255][ks 0..3] -> 1 KB frag
//   chunk for (row gr, k=ks*32+kg*8) at byte ((gr>>4)*4+ks)*1024 + kg*256 + (gr&15)*16
//   reader: frag_base + lane*16  (lane = kg*16 + r16) — verified R9-R12.
// ws layout: XI (4MB) | YI (4MB) | XC (128KB float2: xs, ln(1-xs)) | YC (128KB)
#define WS_XI   0
#define WS_YI   (4u*NN*DK*2u)
#define WS_XC   (2u*WS_YI)
#define WS_YC   (WS_XC + 4u*NN*8u)
#define WS_REQ  (WS_YC + 4u*NN*8u)

__device__ __forceinline__ void load_lds16(const void* g, void* l) {
    __builtin_amdgcn_global_load_lds(
        (const __attribute__((address_space(1))) unsigned int*)g,
        (__attribute__((address_space(3))) unsigned int*)l, 16, 0, 0);
}

// ---------------- pre-pass: f32 -> frag-major bf16 image + (xs, ln(1-xs)) -----
__global__ __launch_bounds__(256)
void prep_kernel(const float* __restrict__ X, const float* __restrict__ Y,
                 __bf16* __restrict__ XI, __bf16* __restrict__ YI,
                 float2* __restrict__ XC, float2* __restrict__ YC)
{
    const int tid = threadIdx.x;
    const int c16 = tid & 15;                 // 8-elem k-chunk index
    const int rl  = tid >> 4;                 // 16 rows per block
    const int gr  = blockIdx.x * 16 + rl;     // row across all batches

    const float* src = blockIdx.y ? Y : X;
    __bf16*      dst = blockIdx.y ? YI : XI;
    float2*      nc  = blockIdx.y ? YC : XC;

    const f32x4* s4 = (const f32x4*)(src + (size_t)gr * DK + c16 * 8);
    f32x4 v0 = s4[0], v1 = s4[1];
    float s = v0[0]*v0[0] + v0[1]*v0[1] + v0[2]*v0[2] + v0[3]*v0[3]
            + v1[0]*v1[0] + v1[1]*v1[1] + v1[2]*v1[2] + v1[3]*v1[3];
    s += __shfl_xor(s, 1);
    s += __shfl_xor(s, 2);
    s += __shfl_xor(s, 4);
    s += __shfl_xor(s, 8);

    bf16x8 pk;
    pk[0]=(__bf16)v0[0]; pk[1]=(__bf16)v0[1]; pk[2]=(__bf16)v0[2]; pk[3]=(__bf16)v0[3];
    pk[4]=(__bf16)v1[0]; pk[5]=(__bf16)v1[1]; pk[6]=(__bf16)v1[2]; pk[7]=(__bf16)v1[3];

    const int bz = gr >> 12;                  // batch
    const int gl = gr & (NN - 1);             // row within batch
    const int ks = c16 >> 2, kg = c16 & 3;
    char* img = (char*)dst + (size_t)bz * (NN * DK * 2);
    const int off = (((gl >> 4) * 4 + ks) << 10) + kg * 256 + (gl & 15) * 16;
    *(bf16x8*)(img + off) = pk;

    if (c16 == 0) nc[gr] = make_float2(s, __logf(1.0f - s));
}

// ---------------- main: 128x256 per block (two sequential 128-col halves) -----
// x via LDS DMA (once), y-frags in registers per half. LDS 38 KB -> 4 blocks/CU.
__global__ __launch_bounds__(512, 4)
void hyp_main(const __bf16* __restrict__ XI, const __bf16* __restrict__ YI,
              const float2* __restrict__ XC, const float2* __restrict__ YC,
              float* __restrict__ Out)
{
    __shared__ alignas(16) char aL[32 * 1024];   // x-tile frag-major image
    __shared__ float2 xcL[128];                  // (xs, ln(1-xs))
    __shared__ float2 ycL[256];

    // XCD-bijective swizzle over the linear grid (nwg = 2048, %8 == 0).
    const int cpx = gridDim.x >> 3;
    const int bid = blockIdx.x;
    const int swz = (bid & 7) * cpx + (bid >> 3);
    const int bx  = swz & 15;                    // 256-col tile (fastest)
    const int by  = (swz >> 4) & 31;             // 128-row tile
    const int bz  = swz >> 9;                    // batch

    const int tid  = threadIdx.x;
    const int lane = tid & 63;
    const int wid  = tid >> 6;
    const int brow = by * 128;
    const int bcol = bx * 256;

    const char* ximg = (const char*)XI + (size_t)bz * (NN * DK * 2);
    const char* yimg = (const char*)YI + (size_t)bz * (NN * DK * 2);

    // DMA the 32 KB x row-tile image into LDS (linear, conflict-free).
    {
        const char* xt = ximg + ((size_t)(brow >> 4) << 12);
        const int woff = wid * 4096;
#pragma unroll
        for (int p = 0; p < 4; ++p)
            load_lds16(xt + woff + p * 1024 + lane * 16, aL + woff + p * 1024);
    }
    if (tid < 128)       xcL[tid]       = XC[bz * NN + brow + tid];
    else if (tid < 384)  ycL[tid - 128] = YC[bz * NN + bcol + (tid - 128)];

    const int wm  = wid >> 2;   // 2x4 wave grid per half: 64 rows x 32 cols
    const int wn  = wid & 3;
    const int r16 = lane & 15;
    const int kg  = lane >> 4;

    __syncthreads();   // drain x-DMA + table writes

    float* ob = Out + ((size_t)bz * NN + brow) * NN + bcol;

#pragma unroll 1      // keep halves sequential: one bg set live at a time
    for (int h = 0; h < 2; ++h) {
        // Hoist this half's y-fragments (8 coalesced 1 KB loads / wave).
        bf16x8 bg[4][2];
        const int ycb = ((bcol + h * 128) >> 4) + wn * 2;
#pragma unroll
        for (int ks = 0; ks < 4; ++ks)
#pragma unroll
            for (int j = 0; j < 2; ++j)
                bg[ks][j] = *(const bf16x8*)(yimg + ((((ycb + j) * 4 + ks) << 10) + lane * 16));

        // Per-slab: 4 ds_reads + 8 MFMA + epilogue + 2 stores.
#pragma unroll
        for (int i = 0; i < 4; ++i) {
            const int rb = wm * 4 + i;         // local 16-rowblock
            f32x4 acc[2] = {};
#pragma unroll
            for (int ks = 0; ks < 4; ++ks) {
                const bf16x8 af = *(const bf16x8*)(aL + (((rb * 4 + ks) << 10) + lane * 16));
                // A=y-frag, B=x-frag: lane's 4 acc regs = 4 consecutive cols.
#pragma unroll
                for (int j = 0; j < 2; ++j)
                    acc[j] = __builtin_amdgcn_mfma_f32_16x16x32_bf16(bg[ks][j], af, acc[j], 0, 0, 0);
            }

            // Epilogue: s = u+v-2d, den = 1-2d+uv, den-s = (1-u)(1-v) exactly:
            // out = ln(den + s + 2*sqrt(s*den)) - ln(1-u) - ln(1-v).
            const int r = wm * 64 + i * 16 + r16;
            const float2 xc = xcL[r];
            const float u = xc.x, cx = xc.y;
            float* orow = ob + (size_t)r * NN + h * 128;
#pragma unroll
            for (int j = 0; j < 2; ++j) {
                const int cb = wn * 32 + j * 16 + kg * 4;
                const f32x4 y01 = *(const f32x4*)&ycL[h * 128 + cb];       // v0,c0,v1,c1
                const f32x4 y23 = *(const f32x4*)&ycL[h * 128 + cb + 2];   // v2,c2,v3,c3
                f32x4 o4;
#pragma unroll
                for (int q = 0; q < 4; ++q) {
                    const float d  = acc[j][q];
                    const float v  = (q < 2) ? y01[2 * q] : y23[2 * (q - 2)];
                    const float cy = (q < 2) ? y01[2 * q + 1] : y23[2 * (q - 2) + 1];
                    const float e1  = fmaf(-2.0f, d, 1.0f);
                    const float den = fmaf(u, v, e1);
                    float s = fmaf(-2.0f, d, u + v);
                    s = fmaxf(s, 1e-12f);
                    const float rt  = __builtin_amdgcn_sqrtf(s * den);
                    const float arg = fmaf(2.0f, rt, den + s);
                    o4[q] = fmaf(__log2f(arg), LN2F, -(cx + cy));
                }
                *(f32x4*)(orow + cb) = o4;
            }
        }
    }
}

// ---------------- fallback (proven R3 structure) if ws is too small ----------
__global__ __launch_bounds__(512, 4)
void hyp_fallback(const float* __restrict__ X, const float* __restrict__ Y,
                  float* __restrict__ Out)
{
    __shared__ alignas(16) __bf16 aL[128 * DK];
    __shared__ alignas(16) __bf16 bL[128 * DK];
    __shared__ float xsL[128];
    __shared__ float ysL[128];

    const int tid  = threadIdx.x;
    const int bz   = blockIdx.z;
    const int brow = blockIdx.y * 128;
    const int bcol = blockIdx.x * 128;
    const float* xb = X + ((size_t)bz * NN + brow) * DK;
    const float* yb = Y + ((size_t)bz * NN + bcol) * DK;
    const int c16 = tid & 15;
    const int rr  = tid >> 4;

#pragma unroll
    for (int p = 0; p < 4; ++p) {
        const int r = p * 32 + rr;
        const f32x4* s4 = (const f32x4*)(xb + r * DK + c16 * 8);
        f32x4 v0 = s4[0], v1 = s4[1];
        float s = v0[0]*v0[0] + v0[1]*v0[1] + v0[2]*v0[2] + v0[3]*v0[3]
                + v1[0]*v1[0] + v1[1]*v1[1] + v1[2]*v1[2] + v1[3]*v1[3];
        s += __shfl_xor(s, 1); s += __shfl_xor(s, 2);
        s += __shfl_xor(s, 4); s += __shfl_xor(s, 8);
        if (c16 == 0) xsL[r] = s;
        bf16x8 pk;
        pk[0]=(__bf16)v0[0]; pk[1]=(__bf16)v0[1]; pk[2]=(__bf16)v0[2]; pk[3]=(__bf16)v0[3];
        pk[4]=(__bf16)v1[0]; pk[5]=(__bf16)v1[1]; pk[6]=(__bf16)v1[2]; pk[7]=(__bf16)v1[3];
        const int byt = (r * 256 + c16 * 16) ^ ((r & 7) << 4);
        *(bf16x8*)((char*)aL + byt) = pk;
    }
#pragma unroll
    for (int p = 0; p < 4; ++p) {
        const int r = p * 32 + rr;
        const f32x4* s4 = (const f32x4*)(yb + r * DK + c16 * 8);
        f32x4 v0 = s4[0], v1 = s4[1];
        float s = v0[0]*v0[0] + v0[1]*v0[1] + v0[2]*v0[2] + v0[3]*v0[3]
                + v1[0]*v1[0] + v1[1]*v1[1] + v1[2]*v1[2] + v1[3]*v1[3];
        s += __shfl_xor(s, 1); s += __shfl_xor(s, 2);
        s += __shfl_xor(s, 4); s += __shfl_xor(s, 8);
        if (c16 == 0) ysL[r] = s;
        bf16x8 pk;
        pk[0]=(__bf16)v0[0]; pk[1]=(__bf16)v0[1]; pk[2]=(__bf16)v0[2]; pk[3]=(__bf16)v0[3];
        pk[4]=(__bf16)v1[0]; pk[5]=(__bf16)v1[1]; pk[6]=(__bf16)v1[2]; pk[7]=(__bf16)v1[3];
        const int byt = (r * 256 + c16 * 16) ^ ((r & 7) << 4);
        *(bf16x8*)((char*)bL + byt) = pk;
    }
    __syncthreads();

    const int lane = tid & 63;
    const int wid  = tid >> 6;
    const int wm   = wid >> 2;
    const int wn   = wid & 3;
    const int r16  = lane & 15;
    const int kg   = lane >> 4;
    f32x4 acc[4][2] = {};
#pragma unroll
    for (int ks = 0; ks < 4; ++ks) {
        const int kb = ks * 32 + kg * 8;
        bf16x8 af[4], bg[2];
#pragma unroll
        for (int i = 0; i < 4; ++i) {
            const int r = wm * 64 + i * 16 + r16;
            const int byt = (r * 256 + kb * 2) ^ ((r & 7) << 4);
            af[i] = *(const bf16x8*)((const char*)aL + byt);
        }
#pragma unroll
        for (int j = 0; j < 2; ++j) {
            const int r = wn * 32 + j * 16 + r16;
            const int byt = (r * 256 + kb * 2) ^ ((r & 7) << 4);
            bg[j] = *(const bf16x8*)((const char*)bL + byt);
        }
#pragma unroll
        for (int i = 0; i < 4; ++i)
#pragma unroll
            for (int j = 0; j < 2; ++j)
                acc[i][j] = __builtin_amdgcn_mfma_f32_16x16x32_bf16(bg[j], af[i], acc[i][j], 0, 0, 0);
    }
    float* ob = Out + ((size_t)bz * NN + brow) * NN + bcol;
#pragma unroll
    for (int i = 0; i < 4; ++i) {
        const int r = wm * 64 + i * 16 + r16;
        const float u = xsL[r];
        float* orow = ob + (size_t)r * NN;
#pragma unroll
        for (int j = 0; j < 2; ++j) {
            const int cb = wn * 32 + j * 16 + kg * 4;
            const f32x4 v4 = *(const f32x4*)&ysL[cb];
            f32x4 o4;
#pragma unroll
            for (int q = 0; q < 4; ++q) {
                const float d  = acc[i][j][q];
                const float v  = v4[q];
                const float e1 = fmaf(-2.0f, d, 1.0f);
                const float den = fmaf(u, v, e1);
                float s = fmaf(-2.0f, d, u + v);
                s = fmaxf(s, 1e-12f);
                const float dn0 = s * __builtin_amdgcn_rsqf(s * den);
                const float dn = fminf(dn0, NMAX);
                o4[q] = __logf((1.0f + dn) * __builtin_amdgcn_rcpf(1.0f - dn));
            }
            *(f32x4*)(orow + cb) = o4;
        }
    }
}

extern "C" void kernel_launch(void* const* d_in, const int* in_sizes, int n_in,
                              void* d_out, int out_size, void* d_ws, size_t ws_size,
                              hipStream_t stream) {
    const float* X = (const float*)d_in[0];
    const float* Y = (const float*)d_in[1];
    float* O = (float*)d_out;
    const int b = in_sizes[0] / (NN * DK);   // = 4

    if (ws_size >= WS_REQ) {
        __bf16* XI = (__bf16*)((char*)d_ws + WS_XI);
        __bf16* YI = (__bf16*)((char*)d_ws + WS_YI);
        float2* XC = (float2*)((char*)d_ws + WS_XC);
        float2* YC = (float2*)((char*)d_ws + WS_YC);
        dim3 pg(b * NN / 16, 2, 1);
        prep_kernel<<<pg, dim3(256), 0, stream>>>(X, Y, XI, YI, XC, YC);
        const int nwg = b * 32 * 16;         // 2048, XCD-swizzled in-kernel
        hyp_main<<<dim3(nwg), dim3(512), 0, stream>>>(XI, YI, XC, YC, O);
    } else {
        dim3 grid(NN / 128, NN / 128, b);
        hyp_fallback<<<grid, dim3(512), 0, stream>>>(X, Y, O);
    }
}

// Round 14
// 67.382 us; speedup vs baseline: 1.5883x; 1.5883x over previous
//
#include <hip/hip_runtime.h>
#include <hip/hip_bf16.h>

typedef __bf16 bf16x8 __attribute__((ext_vector_type(8)));
typedef float  f32x4  __attribute__((ext_vector_type(4)));

#define NN 4096
#define DK 128
#define NMAX 0.99f
#define LN2F 0.69314718056f

// frag-major bf16 image, per batch (1 MB): [rowblk 0..255][ks 0..3] -> 1 KB frag
//   chunk for (row gr, k=ks*32+kg*8) at byte ((gr>>4)*4+ks)*1024 + kg*256 + (gr&15)*16
//   reader: frag_base + lane*16  (lane = kg*16 + r16) — verified R9-R12.
// ws layout: XI (4MB) | YI (4MB) | XC (128KB float2: xs, ln(1-xs)) | YC (128KB)
#define WS_XI   0
#define WS_YI   (4u*NN*DK*2u)
#define WS_XC   (2u*WS_YI)
#define WS_YC   (WS_XC + 4u*NN*8u)
#define WS_REQ  (WS_YC + 4u*NN*8u)

__device__ __forceinline__ void load_lds16(const void* g, void* l) {
    __builtin_amdgcn_global_load_lds(
        (const __attribute__((address_space(1))) unsigned int*)g,
        (__attribute__((address_space(3))) unsigned int*)l, 16, 0, 0);
}

// ---------------- pre-pass: f32 -> frag-major bf16 image + (xs, ln(1-xs)) -----
__global__ __launch_bounds__(256)
void prep_kernel(const float* __restrict__ X, const float* __restrict__ Y,
                 __bf16* __restrict__ XI, __bf16* __restrict__ YI,
                 float2* __restrict__ XC, float2* __restrict__ YC)
{
    const int tid = threadIdx.x;
    const int c16 = tid & 15;                 // 8-elem k-chunk index
    const int rl  = tid >> 4;                 // 16 rows per block
    const int gr  = blockIdx.x * 16 + rl;     // row across all batches

    const float* src = blockIdx.y ? Y : X;
    __bf16*      dst = blockIdx.y ? YI : XI;
    float2*      nc  = blockIdx.y ? YC : XC;

    const f32x4* s4 = (const f32x4*)(src + (size_t)gr * DK + c16 * 8);
    f32x4 v0 = s4[0], v1 = s4[1];
    float s = v0[0]*v0[0] + v0[1]*v0[1] + v0[2]*v0[2] + v0[3]*v0[3]
            + v1[0]*v1[0] + v1[1]*v1[1] + v1[2]*v1[2] + v1[3]*v1[3];
    s += __shfl_xor(s, 1);
    s += __shfl_xor(s, 2);
    s += __shfl_xor(s, 4);
    s += __shfl_xor(s, 8);

    bf16x8 pk;
    pk[0]=(__bf16)v0[0]; pk[1]=(__bf16)v0[1]; pk[2]=(__bf16)v0[2]; pk[3]=(__bf16)v0[3];
    pk[4]=(__bf16)v1[0]; pk[5]=(__bf16)v1[1]; pk[6]=(__bf16)v1[2]; pk[7]=(__bf16)v1[3];

    const int bz = gr >> 12;                  // batch
    const int gl = gr & (NN - 1);             // row within batch
    const int ks = c16 >> 2, kg = c16 & 3;
    char* img = (char*)dst + (size_t)bz * (NN * DK * 2);
    const int off = (((gl >> 4) * 4 + ks) << 10) + kg * 256 + (gl & 15) * 16;
    *(bf16x8*)(img + off) = pk;

    if (c16 == 0) nc[gr] = make_float2(s, __logf(1.0f - s));
}

// Per-tile compute+store (inlined twice). aT = this tile's 32 KB LDS image,
// rowoff = 0 or 128 within the block's 256-row span.
__device__ __forceinline__ void tile_compute(
    const char* aT, const bf16x8 (&bg)[4][2], const float2* xcL, const float2* ycL,
    float* ob, int rowoff, int wm, int wn, int r16, int kg, int lane)
{
#pragma unroll
    for (int i = 0; i < 4; ++i) {
        const int rb = wm * 4 + i;         // local 16-rowblock within tile
        f32x4 acc[2] = {};
#pragma unroll
        for (int ks = 0; ks < 4; ++ks) {
            const bf16x8 af = *(const bf16x8*)(aT + (((rb * 4 + ks) << 10) + lane * 16));
            // A=y-frag, B=x-frag: lane's 4 acc regs = 4 consecutive out cols.
#pragma unroll
            for (int j = 0; j < 2; ++j)
                acc[j] = __builtin_amdgcn_mfma_f32_16x16x32_bf16(bg[ks][j], af, acc[j], 0, 0, 0);
        }

        // Epilogue: s = u+v-2d, den = 1-2d+uv, den-s = (1-u)(1-v) exactly:
        // out = ln(den + s + 2*sqrt(s*den)) - ln(1-u) - ln(1-v).
        const int r = wm * 64 + i * 16 + r16;
        const float2 xc = xcL[rowoff + r];
        const float u = xc.x, cx = xc.y;
        float* orow = ob + (size_t)(rowoff + r) * NN;
#pragma unroll
        for (int j = 0; j < 2; ++j) {
            const int cb = wn * 32 + j * 16 + kg * 4;
            const f32x4 y01 = *(const f32x4*)&ycL[cb];       // v0,c0,v1,c1
            const f32x4 y23 = *(const f32x4*)&ycL[cb + 2];   // v2,c2,v3,c3
            f32x4 o4;
#pragma unroll
            for (int q = 0; q < 4; ++q) {
                const float d  = acc[j][q];
                const float v  = (q < 2) ? y01[2 * q] : y23[2 * (q - 2)];
                const float cy = (q < 2) ? y01[2 * q + 1] : y23[2 * (q - 2) + 1];
                const float e1  = fmaf(-2.0f, d, 1.0f);
                const float den = fmaf(u, v, e1);
                float s = fmaf(-2.0f, d, u + v);
                s = fmaxf(s, 1e-12f);
                const float rt  = __builtin_amdgcn_sqrtf(s * den);
                const float arg = fmaf(2.0f, rt, den + s);
                o4[q] = fmaf(__log2f(arg), LN2F, -(cx + cy));
            }
            *(f32x4*)(orow + cb) = o4;
        }
    }
}

// ---------------- main: 256x128 per block, two pipelined 128-row tiles --------
// DMA1 issues right after the first barrier -> hides under tile0 compute+store.
// LDS 67 KB -> 2 blocks/CU (16 waves/CU). y-frags/tables loaded once per block.
__global__ __launch_bounds__(512, 4)
void hyp_main(const __bf16* __restrict__ XI, const __bf16* __restrict__ YI,
              const float2* __restrict__ XC, const float2* __restrict__ YC,
              float* __restrict__ Out)
{
    __shared__ alignas(16) char aL[2][32 * 1024];  // x-tile frag-major images
    __shared__ float2 xcL[256];                    // (xs, ln(1-xs)) for 256 rows
    __shared__ float2 ycL[128];

    // XCD-bijective swizzle over the linear grid (nwg = 2048, %8 == 0).
    const int cpx = gridDim.x >> 3;
    const int bid = blockIdx.x;
    const int swz = (bid & 7) * cpx + (bid >> 3);
    const int bx  = swz & 31;                    // col-tile (fastest)
    const int by  = (swz >> 5) & 15;             // 256-row pair tile
    const int bz  = swz >> 9;                    // batch

    const int tid  = threadIdx.x;
    const int lane = tid & 63;
    const int wid  = tid >> 6;
    const int brow = by * 256;
    const int bcol = bx * 128;

    const char* ximg = (const char*)XI + (size_t)bz * (NN * DK * 2);
    const char* yimg = (const char*)YI + (size_t)bz * (NN * DK * 2);
    const char* xt   = ximg + ((size_t)(brow >> 4) << 12);   // 64 KB (both tiles)

    // DMA tile0's 32 KB x-image into LDS (linear, conflict-free).
    {
        const int woff = wid * 4096;
#pragma unroll
        for (int p = 0; p < 4; ++p)
            load_lds16(xt + woff + p * 1024 + lane * 16, aL[0] + woff + p * 1024);
    }
    if (tid < 256)       xcL[tid]       = XC[bz * NN + brow + tid];
    else if (tid < 384)  ycL[tid - 256] = YC[bz * NN + bcol + (tid - 256)];

    const int wm  = wid >> 2;   // 2x4 wave grid per tile: 64 rows x 32 cols
    const int wn  = wid & 3;
    const int r16 = lane & 15;
    const int kg  = lane >> 4;

    // y-fragments, loaded once, reused for both tiles.
    bf16x8 bg[4][2];
    const int ycb = (bcol >> 4) + wn * 2;
#pragma unroll
    for (int ks = 0; ks < 4; ++ks)
#pragma unroll
        for (int j = 0; j < 2; ++j)
            bg[ks][j] = *(const bf16x8*)(yimg + ((((ycb + j) * 4 + ks) << 10) + lane * 16));

    __syncthreads();   // tile0 image + tables + y-frags ready

    // Prefetch tile1's 32 KB image NOW — hides under tile0 compute+stores.
    {
        const int woff = wid * 4096;
#pragma unroll
        for (int p = 0; p < 4; ++p)
            load_lds16(xt + 32768 + woff + p * 1024 + lane * 16, aL[1] + woff + p * 1024);
    }

    float* ob = Out + ((size_t)bz * NN + brow) * NN + bcol;

    tile_compute(aL[0], bg, xcL, ycL, ob, 0,   wm, wn, r16, kg, lane);

    __syncthreads();   // drains tile1 DMA (vmcnt) across all waves

    tile_compute(aL[1], bg, xcL, ycL, ob, 128, wm, wn, r16, kg, lane);
}

// ---------------- fallback (proven R3 structure) if ws is too small ----------
__global__ __launch_bounds__(512, 4)
void hyp_fallback(const float* __restrict__ X, const float* __restrict__ Y,
                  float* __restrict__ Out)
{
    __shared__ alignas(16) __bf16 aL[128 * DK];
    __shared__ alignas(16) __bf16 bL[128 * DK];
    __shared__ float xsL[128];
    __shared__ float ysL[128];

    const int tid  = threadIdx.x;
    const int bz   = blockIdx.z;
    const int brow = blockIdx.y * 128;
    const int bcol = blockIdx.x * 128;
    const float* xb = X + ((size_t)bz * NN + brow) * DK;
    const float* yb = Y + ((size_t)bz * NN + bcol) * DK;
    const int c16 = tid & 15;
    const int rr  = tid >> 4;

#pragma unroll
    for (int p = 0; p < 4; ++p) {
        const int r = p * 32 + rr;
        const f32x4* s4 = (const f32x4*)(xb + r * DK + c16 * 8);
        f32x4 v0 = s4[0], v1 = s4[1];
        float s = v0[0]*v0[0] + v0[1]*v0[1] + v0[2]*v0[2] + v0[3]*v0[3]
                + v1[0]*v1[0] + v1[1]*v1[1] + v1[2]*v1[2] + v1[3]*v1[3];
        s += __shfl_xor(s, 1); s += __shfl_xor(s, 2);
        s += __shfl_xor(s, 4); s += __shfl_xor(s, 8);
        if (c16 == 0) xsL[r] = s;
        bf16x8 pk;
        pk[0]=(__bf16)v0[0]; pk[1]=(__bf16)v0[1]; pk[2]=(__bf16)v0[2]; pk[3]=(__bf16)v0[3];
        pk[4]=(__bf16)v1[0]; pk[5]=(__bf16)v1[1]; pk[6]=(__bf16)v1[2]; pk[7]=(__bf16)v1[3];
        const int byt = (r * 256 + c16 * 16) ^ ((r & 7) << 4);
        *(bf16x8*)((char*)aL + byt) = pk;
    }
#pragma unroll
    for (int p = 0; p < 4; ++p) {
        const int r = p * 32 + rr;
        const f32x4* s4 = (const f32x4*)(yb + r * DK + c16 * 8);
        f32x4 v0 = s4[0], v1 = s4[1];
        float s = v0[0]*v0[0] + v0[1]*v0[1] + v0[2]*v0[2] + v0[3]*v0[3]
                + v1[0]*v1[0] + v1[1]*v1[1] + v1[2]*v1[2] + v1[3]*v1[3];
        s += __shfl_xor(s, 1); s += __shfl_xor(s, 2);
        s += __shfl_xor(s, 4); s += __shfl_xor(s, 8);
        if (c16 == 0) ysL[r] = s;
        bf16x8 pk;
        pk[0]=(__bf16)v0[0]; pk[1]=(__bf16)v0[1]; pk[2]=(__bf16)v0[2]; pk[3]=(__bf16)v0[3];
        pk[4]=(__bf16)v1[0]; pk[5]=(__bf16)v1[1]; pk[6]=(__bf16)v1[2]; pk[7]=(__bf16)v1[3];
        const int byt = (r * 256 + c16 * 16) ^ ((r & 7) << 4);
        *(bf16x8*)((char*)bL + byt) = pk;
    }
    __syncthreads();

    const int lane = tid & 63;
    const int wid  = tid >> 6;
    const int wm   = wid >> 2;
    const int wn   = wid & 3;
    const int r16  = lane & 15;
    const int kg   = lane >> 4;
    f32x4 acc[4][2] = {};
#pragma unroll
    for (int ks = 0; ks < 4; ++ks) {
        const int kb = ks * 32 + kg * 8;
        bf16x8 af[4], bg[2];
#pragma unroll
        for (int i = 0; i < 4; ++i) {
            const int r = wm * 64 + i * 16 + r16;
            const int byt = (r * 256 + kb * 2) ^ ((r & 7) << 4);
            af[i] = *(const bf16x8*)((const char*)aL + byt);
        }
#pragma unroll
        for (int j = 0; j < 2; ++j) {
            const int r = wn * 32 + j * 16 + r16;
            const int byt = (r * 256 + kb * 2) ^ ((r & 7) << 4);
            bg[j] = *(const bf16x8*)((const char*)bL + byt);
        }
#pragma unroll
        for (int i = 0; i < 4; ++i)
#pragma unroll
            for (int j = 0; j < 2; ++j)
                acc[i][j] = __builtin_amdgcn_mfma_f32_16x16x32_bf16(bg[j], af[i], acc[i][j], 0, 0, 0);
    }
    float* ob = Out + ((size_t)bz * NN + brow) * NN + bcol;
#pragma unroll
    for (int i = 0; i < 4; ++i) {
        const int r = wm * 64 + i * 16 + r16;
        const float u = xsL[r];
        float* orow = ob + (size_t)r * NN;
#pragma unroll
        for (int j = 0; j < 2; ++j) {
            const int cb = wn * 32 + j * 16 + kg * 4;
            const f32x4 v4 = *(const f32x4*)&ysL[cb];
            f32x4 o4;
#pragma unroll
            for (int q = 0; q < 4; ++q) {
                const float d  = acc[i][j][q];
                const float v  = v4[q];
                const float e1 = fmaf(-2.0f, d, 1.0f);
                const float den = fmaf(u, v, e1);
                float s = fmaf(-2.0f, d, u + v);
                s = fmaxf(s, 1e-12f);
                const float dn0 = s * __builtin_amdgcn_rsqf(s * den);
                const float dn = fminf(dn0, NMAX);
                o4[q] = __logf((1.0f + dn) * __builtin_amdgcn_rcpf(1.0f - dn));
            }
            *(f32x4*)(orow + cb) = o4;
        }
    }
}

extern "C" void kernel_launch(void* const* d_in, const int* in_sizes, int n_in,
                              void* d_out, int out_size, void* d_ws, size_t ws_size,
                              hipStream_t stream) {
    const float* X = (const float*)d_in[0];
    const float* Y = (const float*)d_in[1];
    float* O = (float*)d_out;
    const int b = in_sizes[0] / (NN * DK);   // = 4

    if (ws_size >= WS_REQ) {
        __bf16* XI = (__bf16*)((char*)d_ws + WS_XI);
        __bf16* YI = (__bf16*)((char*)d_ws + WS_YI);
        float2* XC = (float2*)((char*)d_ws + WS_XC);
        float2* YC = (float2*)((char*)d_ws + WS_YC);
        dim3 pg(b * NN / 16, 2, 1);
        prep_kernel<<<pg, dim3(256), 0, stream>>>(X, Y, XI, YI, XC, YC);
        const int nwg = b * 16 * 32;         // 2048, XCD-swizzled in-kernel
        hyp_main<<<dim3(nwg), dim3(512), 0, stream>>>(XI, YI, XC, YC, O);
    } else {
        dim3 grid(NN / 128, NN / 128, b);
        hyp_fallback<<<grid, dim3(512), 0, stream>>>(X, Y, O);
    }
}